// Round 1
// baseline (494.552 us; speedup 1.0000x reference)
//
#include <hip/hip_runtime.h>

#define DF 128
constexpr int N_NODES = 10000;
constexpr int N_EDGES = 640000;

typedef __bf16 bf16x8 __attribute__((ext_vector_type(8)));
typedef float f32x4 __attribute__((ext_vector_type(4)));

// ---------- helpers ----------
__device__ __forceinline__ unsigned short f2bf(float f) {
  unsigned u = __builtin_bit_cast(unsigned, f);
  u += 0x7fffu + ((u >> 16) & 1u);   // RTNE
  return (unsigned short)(u >> 16);
}

__device__ __forceinline__ bf16x8 cvt8(float4 a, float4 b) {
  bf16x8 r;
  r[0] = (__bf16)a.x; r[1] = (__bf16)a.y; r[2] = (__bf16)a.z; r[3] = (__bf16)a.w;
  r[4] = (__bf16)b.x; r[5] = (__bf16)b.y; r[6] = (__bf16)b.z; r[7] = (__bf16)b.w;
  return r;
}

// stage a 16x128 C-layout tile (relu'd) into a 4KB LDS buffer, XOR-swizzled
__device__ __forceinline__ void stage_h(char* bufj, const f32x4* accv, int grp, int row16) {
#pragma unroll
  for (int nt = 0; nt < 8; ++nt)
#pragma unroll
    for (int i = 0; i < 4; ++i) {
      const int r = grp * 4 + i;
      const int c = nt * 16 + row16;
      *(unsigned short*)(bufj + ((r * 256 + c * 2) ^ ((r & 7) << 4))) =
          f2bf(fmaxf(accv[nt][i], 0.f));
    }
}

// read an A-fragment (16 rows x 32 k) from a swizzled 4KB buffer
__device__ __forceinline__ bf16x8 read_a(const char* bufj, int kt, int grp, int row16) {
  return *(const bf16x8*)(bufj + ((row16 * 256 + kt * 64 + grp * 16) ^ ((row16 & 7) << 4)));
}

// ---------- kernel 1: pack all weights to bf16 in MFMA-B-fragment order ----------
// layout: elem index p for a [K][128] weight: p = ((kt*8+nt)*64 + lane)*8 + i
// with k = kt*32 + (lane>>4)*8 + i, n = nt*16 + (lane&15)
__global__ void pack_weights(const float* __restrict__ w0, const float* __restrict__ w1,
                             const float* __restrict__ w2, const float* __restrict__ nw0,
                             const float* __restrict__ nw1, const float* __restrict__ nw2,
                             const float* __restrict__ wn, unsigned short* __restrict__ dst) {
  int tid = blockIdx.x * blockDim.x + threadIdx.x;
  if (tid >= 163840) return;
  const float* src; int p;
  if (tid < 49152)       { src = w0;  p = tid; }
  else if (tid < 65536)  { src = w1;  p = tid - 49152; }
  else if (tid < 81920)  { src = w2;  p = tid - 65536; }
  else if (tid < 114688) { src = nw0; p = tid - 81920; }
  else if (tid < 131072) { src = nw1; p = tid - 114688; }
  else if (tid < 147456) { src = nw2; p = tid - 131072; }
  else                   { src = wn;  p = tid - 147456; }
  int i = p & 7, lane = (p >> 3) & 63, tile = p >> 9;
  int nt = tile & 7, kt = tile >> 3;
  int k = kt * 32 + ((lane >> 4) << 3) + i;
  int n = nt * 16 + (lane & 15);
  dst[tid] = f2bf(src[k * 128 + n]);
}

// ---------- kernel 2: fused message MLP + scatter-add ----------
// grid 1250 x 512 threads (8 waves), 512 edges/block, 64 edges/wave (4 subtiles of 16)
__global__ void __launch_bounds__(512) msg_kernel(
    const float* __restrict__ nodes, const float* __restrict__ edges,
    const int* __restrict__ senders, const int* __restrict__ receivers,
    const float* __restrict__ b0, const float* __restrict__ b1, const float* __restrict__ b2,
    const unsigned short* __restrict__ pw, float* __restrict__ agg) {
  extern __shared__ char lds[];
  char* w0c = lds;            // 98304 B  (frag-packed msg_w0)
  char* w1c = lds + 98304;    // 32768 B
  char* w2c = lds + 131072;   // 32768 B
  const int tid = threadIdx.x;
  const int lane = tid & 63, wave = tid >> 6;
  const int row16 = lane & 15, grp = lane >> 4;

  // stage all 3 packed weights (160 KB contiguous) into LDS
  {
    const float4* s = (const float4*)pw;
    float4* d = (float4*)lds;
    for (int c = tid; c < 10240; c += 512) d[c] = s[c];
  }
  __syncthreads();

  const int rbase = blockIdx.x * 512 + wave * 64;
  int sidx[4], ridx[4];
#pragma unroll
  for (int s = 0; s < 4; ++s) {
    sidx[s] = senders[rbase + s * 16 + row16];
    ridx[s] = receivers[rbase + s * 16 + row16];
  }

  f32x4 acc[4][8];
#pragma unroll
  for (int nt = 0; nt < 8; ++nt) {
    float bv = b0[nt * 16 + row16];
#pragma unroll
    for (int s = 0; s < 4; ++s) acc[s][nt] = (f32x4){bv, bv, bv, bv};
  }

  // ---- layer 0: K = 384 = [sender | receiver | edge] ----
#pragma unroll
  for (int ktg = 0; ktg < 12; ++ktg) {
    const int kc = ktg >> 2, k2 = ktg & 3;
    bf16x8 bw[8];
#pragma unroll
    for (int nt = 0; nt < 8; ++nt)
      bw[nt] = *(const bf16x8*)(w0c + ((ktg * 8 + nt) * 64 + lane) * 16);
#pragma unroll
    for (int s = 0; s < 4; ++s) {
      const float* p;
      if (kc == 0)      p = nodes + (size_t)sidx[s] * DF;
      else if (kc == 1) p = nodes + (size_t)ridx[s] * DF;
      else              p = edges + (size_t)(rbase + s * 16 + row16) * DF;
      p += k2 * 32 + grp * 8;
      float4 f0 = *(const float4*)p;
      float4 f1 = *(const float4*)(p + 4);
      bf16x8 af = cvt8(f0, f1);
#pragma unroll
      for (int nt = 0; nt < 8; ++nt)
        acc[s][nt] = __builtin_amdgcn_mfma_f32_16x16x32_bf16(af, bw[nt], acc[s][nt], 0, 0, 0);
    }
  }

  __syncthreads();  // every wave done with w0 -> its LDS region is reusable

  char* hb = lds + wave * 8192;  // per-wave 2 x 4KB staging, aliased into w0 region
  float b1v[8], b2v[8];
#pragma unroll
  for (int nt = 0; nt < 8; ++nt) {
    b1v[nt] = b1[nt * 16 + row16];
    b2v[nt] = b2[nt * 16 + row16];
  }

#pragma unroll
  for (int pass = 0; pass < 2; ++pass) {
    // stage relu(h1) for subtiles pass*2, pass*2+1
#pragma unroll
    for (int j = 0; j < 2; ++j) stage_h(hb + j * 4096, acc[pass * 2 + j], grp, row16);
    asm volatile("s_waitcnt lgkmcnt(0)" ::: "memory");
    __builtin_amdgcn_sched_barrier(0);

    // ---- layer 1 ----
    f32x4 acc2[2][8];
#pragma unroll
    for (int j = 0; j < 2; ++j)
#pragma unroll
      for (int nt = 0; nt < 8; ++nt) acc2[j][nt] = (f32x4){b1v[nt], b1v[nt], b1v[nt], b1v[nt]};
#pragma unroll
    for (int kt = 0; kt < 4; ++kt) {
      bf16x8 bw[8];
#pragma unroll
      for (int nt = 0; nt < 8; ++nt)
        bw[nt] = *(const bf16x8*)(w1c + ((kt * 8 + nt) * 64 + lane) * 16);
#pragma unroll
      for (int j = 0; j < 2; ++j) {
        bf16x8 af = read_a(hb + j * 4096, kt, grp, row16);
#pragma unroll
        for (int nt = 0; nt < 8; ++nt)
          acc2[j][nt] = __builtin_amdgcn_mfma_f32_16x16x32_bf16(af, bw[nt], acc2[j][nt], 0, 0, 0);
      }
    }
    asm volatile("s_waitcnt lgkmcnt(0)" ::: "memory");
    __builtin_amdgcn_sched_barrier(0);

    // stage relu(h2), overwriting h1
#pragma unroll
    for (int j = 0; j < 2; ++j) stage_h(hb + j * 4096, acc2[j], grp, row16);
    asm volatile("s_waitcnt lgkmcnt(0)" ::: "memory");
    __builtin_amdgcn_sched_barrier(0);

    // ---- layer 2 (no relu) + scatter ----
    f32x4 acc3[2][8];
#pragma unroll
    for (int j = 0; j < 2; ++j)
#pragma unroll
      for (int nt = 0; nt < 8; ++nt) acc3[j][nt] = (f32x4){b2v[nt], b2v[nt], b2v[nt], b2v[nt]};
#pragma unroll
    for (int kt = 0; kt < 4; ++kt) {
      bf16x8 bw[8];
#pragma unroll
      for (int nt = 0; nt < 8; ++nt)
        bw[nt] = *(const bf16x8*)(w2c + ((kt * 8 + nt) * 64 + lane) * 16);
#pragma unroll
      for (int j = 0; j < 2; ++j) {
        bf16x8 af = read_a(hb + j * 4096, kt, grp, row16);
#pragma unroll
        for (int nt = 0; nt < 8; ++nt)
          acc3[j][nt] = __builtin_amdgcn_mfma_f32_16x16x32_bf16(af, bw[nt], acc3[j][nt], 0, 0, 0);
      }
    }
    asm volatile("s_waitcnt lgkmcnt(0)" ::: "memory");  // h reads done before next pass overwrites
    __builtin_amdgcn_sched_barrier(0);

#pragma unroll
    for (int j = 0; j < 2; ++j) {
      const int s = pass * 2 + j;
      int rr[4];
#pragma unroll
      for (int i = 0; i < 4; ++i) rr[i] = receivers[rbase + s * 16 + grp * 4 + i];
#pragma unroll
      for (int nt = 0; nt < 8; ++nt)
#pragma unroll
        for (int i = 0; i < 4; ++i)
          unsafeAtomicAdd(&agg[(size_t)rr[i] * DF + nt * 16 + row16], acc3[j][nt][i]);
    }
  }
}

// ---------- kernel 3: node MLP + residual + LayerNorm ----------
// grid 157 x 256 threads (4 waves), 16 rows/wave
__global__ void __launch_bounds__(256) node_kernel(
    const float* __restrict__ nodes, const float* __restrict__ agg,
    const float* __restrict__ nb0, const float* __restrict__ nb1, const float* __restrict__ nb2,
    const unsigned short* __restrict__ pnw0, const unsigned short* __restrict__ pnw1,
    const unsigned short* __restrict__ pnw2, const unsigned short* __restrict__ pwn,
    const float* __restrict__ ln_s, const float* __restrict__ ln_b,
    float* __restrict__ out) {
  __shared__ char hs[16384];
  const int tid = threadIdx.x, lane = tid & 63, wave = tid >> 6;
  const int row16 = lane & 15, grp = lane >> 4;
  char* hb = hs + wave * 4096;
  const int rb = blockIdx.x * 64 + wave * 16;
  const int rA = min(rb + row16, N_NODES - 1);

  f32x4 acc[8];
#pragma unroll
  for (int nt = 0; nt < 8; ++nt) {
    float b = nb0[nt * 16 + row16];
    acc[nt] = (f32x4){b, b, b, b};
  }
  // layer 0: K=256 = [nodes | aggregated]
#pragma unroll
  for (int kt = 0; kt < 8; ++kt) {
    const float* p = (kt < 4) ? (nodes + (size_t)rA * DF + kt * 32)
                              : (agg + (size_t)rA * DF + (kt - 4) * 32);
    p += grp * 8;
    float4 f0 = *(const float4*)p, f1 = *(const float4*)(p + 4);
    bf16x8 af = cvt8(f0, f1);
#pragma unroll
    for (int nt = 0; nt < 8; ++nt) {
      bf16x8 bw = *(const bf16x8*)(pnw0 + ((size_t)(kt * 8 + nt) * 64 + lane) * 8);
      acc[nt] = __builtin_amdgcn_mfma_f32_16x16x32_bf16(af, bw, acc[nt], 0, 0, 0);
    }
  }
  stage_h(hb, acc, grp, row16);
  asm volatile("s_waitcnt lgkmcnt(0)" ::: "memory");
  __builtin_amdgcn_sched_barrier(0);

  // layer 1
  f32x4 acc2[8];
#pragma unroll
  for (int nt = 0; nt < 8; ++nt) {
    float b = nb1[nt * 16 + row16];
    acc2[nt] = (f32x4){b, b, b, b};
  }
#pragma unroll
  for (int kt = 0; kt < 4; ++kt) {
    bf16x8 af = read_a(hb, kt, grp, row16);
#pragma unroll
    for (int nt = 0; nt < 8; ++nt) {
      bf16x8 bw = *(const bf16x8*)(pnw1 + ((size_t)(kt * 8 + nt) * 64 + lane) * 8);
      acc2[nt] = __builtin_amdgcn_mfma_f32_16x16x32_bf16(af, bw, acc2[nt], 0, 0, 0);
    }
  }
  asm volatile("s_waitcnt lgkmcnt(0)" ::: "memory");
  __builtin_amdgcn_sched_barrier(0);
  stage_h(hb, acc2, grp, row16);
  asm volatile("s_waitcnt lgkmcnt(0)" ::: "memory");
  __builtin_amdgcn_sched_barrier(0);

  // layer 2 (no relu) + residual nodes @ w_node
  f32x4 acc3[8];
#pragma unroll
  for (int nt = 0; nt < 8; ++nt) {
    float b = nb2[nt * 16 + row16];
    acc3[nt] = (f32x4){b, b, b, b};
  }
#pragma unroll
  for (int kt = 0; kt < 4; ++kt) {
    bf16x8 af = read_a(hb, kt, grp, row16);
#pragma unroll
    for (int nt = 0; nt < 8; ++nt) {
      bf16x8 bw = *(const bf16x8*)(pnw2 + ((size_t)(kt * 8 + nt) * 64 + lane) * 8);
      acc3[nt] = __builtin_amdgcn_mfma_f32_16x16x32_bf16(af, bw, acc3[nt], 0, 0, 0);
    }
  }
  f32x4 accR[8];
#pragma unroll
  for (int nt = 0; nt < 8; ++nt) accR[nt] = (f32x4){0.f, 0.f, 0.f, 0.f};
#pragma unroll
  for (int kt = 0; kt < 4; ++kt) {
    const float* p = nodes + (size_t)rA * DF + kt * 32 + grp * 8;
    float4 f0 = *(const float4*)p, f1 = *(const float4*)(p + 4);
    bf16x8 af = cvt8(f0, f1);
#pragma unroll
    for (int nt = 0; nt < 8; ++nt) {
      bf16x8 bw = *(const bf16x8*)(pwn + ((size_t)(kt * 8 + nt) * 64 + lane) * 8);
      accR[nt] = __builtin_amdgcn_mfma_f32_16x16x32_bf16(af, bw, accR[nt], 0, 0, 0);
    }
  }

  // y = residual + mlp_out ; LayerNorm over the 128 cols of each row
  float y[8][4];
#pragma unroll
  for (int nt = 0; nt < 8; ++nt)
#pragma unroll
    for (int i = 0; i < 4; ++i) y[nt][i] = acc3[nt][i] + accR[nt][i];

  float mean[4], rstd[4];
#pragma unroll
  for (int i = 0; i < 4; ++i) {
    float s = 0.f;
#pragma unroll
    for (int nt = 0; nt < 8; ++nt) s += y[nt][i];
    s += __shfl_xor(s, 1); s += __shfl_xor(s, 2);
    s += __shfl_xor(s, 4); s += __shfl_xor(s, 8);
    mean[i] = s * (1.0f / 128.0f);
  }
#pragma unroll
  for (int i = 0; i < 4; ++i) {
    float v = 0.f;
#pragma unroll
    for (int nt = 0; nt < 8; ++nt) {
      float d = y[nt][i] - mean[i];
      v += d * d;
    }
    v += __shfl_xor(v, 1); v += __shfl_xor(v, 2);
    v += __shfl_xor(v, 4); v += __shfl_xor(v, 8);
    rstd[i] = rsqrtf(v * (1.0f / 128.0f) + 1e-6f);
  }
#pragma unroll
  for (int nt = 0; nt < 8; ++nt) {
    const float ls = ln_s[nt * 16 + row16];
    const float lb = ln_b[nt * 16 + row16];
#pragma unroll
    for (int i = 0; i < 4; ++i) {
      const int r = rb + grp * 4 + i;
      if (r < N_NODES)
        out[(size_t)r * DF + nt * 16 + row16] = (y[nt][i] - mean[i]) * rstd[i] * ls + lb;
    }
  }
}

// ---------- launch ----------
extern "C" void kernel_launch(void* const* d_in, const int* in_sizes, int n_in,
                              void* d_out, int out_size, void* d_ws, size_t ws_size,
                              hipStream_t stream) {
  const float* nodes     = (const float*)d_in[0];
  const float* edges     = (const float*)d_in[1];
  const int*   senders   = (const int*)d_in[2];
  const int*   receivers = (const int*)d_in[3];
  const float* msg_w0 = (const float*)d_in[4];
  const float* msg_b0 = (const float*)d_in[5];
  const float* msg_w1 = (const float*)d_in[6];
  const float* msg_b1 = (const float*)d_in[7];
  const float* msg_w2 = (const float*)d_in[8];
  const float* msg_b2 = (const float*)d_in[9];
  const float* node_w0 = (const float*)d_in[10];
  const float* node_b0 = (const float*)d_in[11];
  const float* node_w1 = (const float*)d_in[12];
  const float* node_b1 = (const float*)d_in[13];
  const float* node_w2 = (const float*)d_in[14];
  const float* node_b2 = (const float*)d_in[15];
  const float* w_node   = (const float*)d_in[16];
  const float* ln_scale = (const float*)d_in[17];
  const float* ln_bias  = (const float*)d_in[18];

  float* agg = (float*)d_ws;
  unsigned short* pw = (unsigned short*)((char*)d_ws + 5120000);
  // packed layout (elems): pw0 @0 (49152) | pw1 @49152 | pw2 @65536 |
  //                        pnw0 @81920 | pnw1 @114688 | pnw2 @131072 | pwn @147456

  hipMemsetAsync(agg, 0, (size_t)N_NODES * DF * sizeof(float), stream);
  pack_weights<<<640, 256, 0, stream>>>(msg_w0, msg_w1, msg_w2, node_w0, node_w1,
                                        node_w2, w_node, pw);

  hipFuncSetAttribute((const void*)msg_kernel,
                      hipFuncAttributeMaxDynamicSharedMemorySize, 163840);
  msg_kernel<<<N_EDGES / 512, 512, 163840, stream>>>(
      nodes, edges, senders, receivers, msg_b0, msg_b1, msg_b2, pw, agg);

  node_kernel<<<157, 256, 0, stream>>>(nodes, agg, node_b0, node_b1, node_b2,
                                       pw + 81920, pw + 114688, pw + 131072, pw + 147456,
                                       ln_scale, ln_bias, (float*)d_out);
}